// Round 1
// baseline (5484.250 us; speedup 1.0000x reference)
//
#include <hip/hip_runtime.h>
#include <hip/hip_bf16.h>

#define SEQ 512
#define BATCH 64
#define IN 256
#define HID 512
#define NG 1536  // 3*HID

typedef short short8 __attribute__((ext_vector_type(8)));
typedef float f32x4 __attribute__((ext_vector_type(4)));

__device__ __forceinline__ unsigned short f2bf(float f) {
    union { float f; unsigned u; } v; v.f = f;
    return (unsigned short)((v.u + 0x7fffu + ((v.u >> 16) & 1u)) >> 16);
}
__device__ __forceinline__ float bf2f(unsigned short h) {
    union { unsigned u; float f; } v; v.u = ((unsigned)h) << 16; return v.f;
}

// Build gate-major bf16 weight blocks + folded bias constants.
// n = g*512 + j, g in {r,u,n}.
// WxT[n][i]  (i<256) : x-side weights
// WhT[n][k]  (k<512) : h-side weights
// biases[n]          : folded constant added to x-projection
//   g=0: Wr[j,256]+Wr[j,769]+br[j] ; g=1: same for Wu/bu ; g=2: Wni[j,256]+bni[j]
// biases[NG+j]       : Wnh[j,512]+bnh[j]  (inside the r* term)
__global__ void prep_weights(const float* __restrict__ Wr, const float* __restrict__ br,
                             const float* __restrict__ Wu, const float* __restrict__ bu,
                             const float* __restrict__ Wni, const float* __restrict__ bni,
                             const float* __restrict__ Wnh, const float* __restrict__ bnh,
                             unsigned short* __restrict__ WxT, unsigned short* __restrict__ WhT,
                             float* __restrict__ biases)
{
    int n = blockIdx.x * blockDim.x + threadIdx.x;
    if (n >= NG) return;
    int g = n >> 9, j = n & 511;
    const float* xsrc; const float* hsrc; float bias;
    if (g == 0)      { xsrc = Wr + (size_t)j*770; hsrc = Wr + (size_t)j*770 + 257;
                       bias = Wr[(size_t)j*770+256] + Wr[(size_t)j*770+769] + br[j]; }
    else if (g == 1) { xsrc = Wu + (size_t)j*770; hsrc = Wu + (size_t)j*770 + 257;
                       bias = Wu[(size_t)j*770+256] + Wu[(size_t)j*770+769] + bu[j]; }
    else             { xsrc = Wni + (size_t)j*257; hsrc = Wnh + (size_t)j*513;
                       bias = Wni[(size_t)j*257+256] + bni[j]; }
    for (int i = 0; i < IN; ++i)  WxT[(size_t)n*IN + i]  = f2bf(xsrc[i]);
    for (int k = 0; k < HID; ++k) WhT[(size_t)n*HID + k] = f2bf(hsrc[k]);
    biases[n] = bias;
    if (g == 2) biases[NG + j] = Wnh[(size_t)j*513 + 512] + bnh[j];
}

__global__ void cvt_x(const float* __restrict__ x, unsigned short* __restrict__ xb, int n)
{
    int i = (blockIdx.x * blockDim.x + threadIdx.x) * 4;
    if (i >= n) return;
    float4 v = *reinterpret_cast<const float4*>(x + i);
    ushort4 o;
    o.x = f2bf(v.x); o.y = f2bf(v.y); o.z = f2bf(v.z); o.w = f2bf(v.w);
    *reinterpret_cast<ushort4*>(xb + i) = o;
}

// Gx[m][n] = sum_i xb[m][i]*WxT[n][i] + biases[n],  m = t*64+b, stored bf16.
// Block: 64(m) x 256(n); each wave 64x64 via 4x4 16x16x32 MFMA frags, K=256.
__global__ __launch_bounds__(256) void gemm_x(const unsigned short* __restrict__ xb,
                                              const unsigned short* __restrict__ WxT,
                                              const float* __restrict__ biases,
                                              unsigned short* __restrict__ Gx)
{
    const int lane = threadIdx.x & 63;
    const int wave = threadIdx.x >> 6;
    const int m0 = blockIdx.x * 64;
    const int n0 = blockIdx.y * 256 + wave * 64;
    const int laneM = lane & 15, laneK8 = (lane >> 4) * 8;
    f32x4 acc[4][4] = {};
#pragma unroll
    for (int k0 = 0; k0 < IN; k0 += 32) {
        short8 A[4], Bf[4];
#pragma unroll
        for (int mi = 0; mi < 4; ++mi)
            A[mi] = *reinterpret_cast<const short8*>(xb + (size_t)(m0 + mi*16 + laneM)*IN + k0 + laneK8);
#pragma unroll
        for (int ni = 0; ni < 4; ++ni)
            Bf[ni] = *reinterpret_cast<const short8*>(WxT + (size_t)(n0 + ni*16 + laneM)*IN + k0 + laneK8);
#pragma unroll
        for (int mi = 0; mi < 4; ++mi)
#pragma unroll
            for (int ni = 0; ni < 4; ++ni)
                acc[mi][ni] = __builtin_amdgcn_mfma_f32_16x16x32_bf16(A[mi], Bf[ni], acc[mi][ni], 0, 0, 0);
    }
    const int crow = (lane >> 4) * 4, ccol = lane & 15;
#pragma unroll
    for (int mi = 0; mi < 4; ++mi)
#pragma unroll
        for (int ni = 0; ni < 4; ++ni) {
            int nn = n0 + ni*16 + ccol;
            float bias = biases[nn];
#pragma unroll
            for (int v = 0; v < 4; ++v) {
                int mm = m0 + mi*16 + crow + v;
                Gx[(size_t)mm * NG + nn] = f2bf(acc[mi][ni][v] + bias);
            }
        }
}

// Persistent recurrent kernel. 128 blocks x 256 threads (cooperative launch).
// Block (mt,jt) owns batch rows mt*16..+16, hidden cols jt*16..+16.
// Waves K-split the 512-deep recurrent dot (3 gates), reduce via LDS.
__global__ __launch_bounds__(256) void gru_seq(const unsigned short* __restrict__ Gx,
                                               const unsigned short* __restrict__ WhT,
                                               const float* __restrict__ biases,
                                               unsigned short* __restrict__ hbf,
                                               float* __restrict__ out,
                                               unsigned* __restrict__ bar)
{
    const int blk = blockIdx.x;
    const int mt = blk >> 5, jt = blk & 31;
    const int m0 = mt * 16, j0 = jt * 16;
    const int lane = threadIdx.x & 63;
    const int wave = threadIdx.x >> 6;
    const int laneM = lane & 15, laneK8 = (lane >> 4) * 8;
    __shared__ float red[4][3][16][16];

    // Preload recurrent weight fragments once (invariant over t).
    short8 Bf[3][4];
#pragma unroll
    for (int g = 0; g < 3; ++g)
#pragma unroll
        for (int kk = 0; kk < 4; ++kk) {
            int n = g * HID + j0 + laneM;
            int k = wave * 128 + kk * 32 + laneK8;
            Bf[g][kk] = *reinterpret_cast<const short8*>(WhT + (size_t)n * HID + k);
        }

    const int row = threadIdx.x >> 4, col = threadIdx.x & 15;
    const int b = m0 + row, j = j0 + col;
    const float cnh = biases[NG + j];
    float h_old = 0.f;
    const size_t gx0 = (size_t)b * NG + j;
    unsigned short pr = Gx[gx0], pu = Gx[gx0 + HID], pn = Gx[gx0 + 2*HID];

    for (int t = 0; t < SEQ; ++t) {
        // Prefetch next step's x-projections (consumed next iteration).
        unsigned short nr = 0, nu = 0, nn2 = 0;
        if (t + 1 < SEQ) {
            size_t gi = gx0 + (size_t)(t + 1) * BATCH * NG;
            nr = Gx[gi]; nu = Gx[gi + HID]; nn2 = Gx[gi + 2*HID];
        }
        // Recurrent GEMM partials over this wave's K-chunk.
        const unsigned short* hcur = hbf + (size_t)(t & 1) * BATCH * HID;
        short8 A[4];
#pragma unroll
        for (int kk = 0; kk < 4; ++kk)
            A[kk] = *reinterpret_cast<const short8*>(hcur + (size_t)(m0 + laneM) * HID + wave*128 + kk*32 + laneK8);
        f32x4 aR = {0,0,0,0}, aU = {0,0,0,0}, aN = {0,0,0,0};
#pragma unroll
        for (int kk = 0; kk < 4; ++kk) {
            aR = __builtin_amdgcn_mfma_f32_16x16x32_bf16(A[kk], Bf[0][kk], aR, 0, 0, 0);
            aU = __builtin_amdgcn_mfma_f32_16x16x32_bf16(A[kk], Bf[1][kk], aU, 0, 0, 0);
            aN = __builtin_amdgcn_mfma_f32_16x16x32_bf16(A[kk], Bf[2][kk], aN, 0, 0, 0);
        }
        const int crow = (lane >> 4) * 4;
#pragma unroll
        for (int v = 0; v < 4; ++v) {
            red[wave][0][crow + v][laneM] = aR[v];
            red[wave][1][crow + v][laneM] = aU[v];
            red[wave][2][crow + v][laneM] = aN[v];
        }
        __syncthreads();
        float rp = red[0][0][row][col] + red[1][0][row][col] + red[2][0][row][col] + red[3][0][row][col];
        float up = red[0][1][row][col] + red[1][1][row][col] + red[2][1][row][col] + red[3][1][row][col];
        float np = red[0][2][row][col] + red[1][2][row][col] + red[2][2][row][col] + red[3][2][row][col];
        float r = 1.f / (1.f + __expf(-(bf2f(pr) + rp)));
        float z = 1.f / (1.f + __expf(-(bf2f(pu) + up)));
        float e = __expf(2.f * (bf2f(pn) + r * (np + cnh)));
        float n = 1.f - 2.f / (e + 1.f);
        float hnew = (1.f - z) * n + z * h_old;
        h_old = hnew;
        out[(size_t)t * BATCH * HID + (size_t)b * HID + j] = hnew;
        hbf[(size_t)((t + 1) & 1) * BATCH * HID + (size_t)b * HID + j] = f2bf(hnew);
        if (t == SEQ - 1) out[(size_t)SEQ * BATCH * HID + (size_t)b * HID + j] = hnew;
        pr = nr; pu = nu; pn = nn2;

        // Grid barrier (sense-reversing, device scope).
        __syncthreads();
        if (threadIdx.x == 0) {
            unsigned g = __hip_atomic_load(bar + 1, __ATOMIC_RELAXED, __HIP_MEMORY_SCOPE_AGENT);
            unsigned old = __hip_atomic_fetch_add(bar, 1u, __ATOMIC_ACQ_REL, __HIP_MEMORY_SCOPE_AGENT);
            if (old == gridDim.x - 1) {
                __hip_atomic_store(bar, 0u, __ATOMIC_RELAXED, __HIP_MEMORY_SCOPE_AGENT);
                __hip_atomic_store(bar + 1, g + 1u, __ATOMIC_RELEASE, __HIP_MEMORY_SCOPE_AGENT);
            } else {
                while (__hip_atomic_load(bar + 1, __ATOMIC_ACQUIRE, __HIP_MEMORY_SCOPE_AGENT) == g) {
                    __builtin_amdgcn_s_sleep(1);
                }
            }
        }
        __syncthreads();
    }
}

extern "C" void kernel_launch(void* const* d_in, const int* in_sizes, int n_in,
                              void* d_out, int out_size, void* d_ws, size_t ws_size,
                              hipStream_t stream)
{
    const float* x   = (const float*)d_in[0];
    const float* Wr  = (const float*)d_in[1];
    const float* br  = (const float*)d_in[2];
    const float* Wu  = (const float*)d_in[3];
    const float* bu  = (const float*)d_in[4];
    const float* Wni = (const float*)d_in[5];
    const float* bni = (const float*)d_in[6];
    const float* Wnh = (const float*)d_in[7];
    const float* bnh = (const float*)d_in[8];
    float* out = (float*)d_out;

    char* ws = (char*)d_ws;
    size_t off = 0;
    unsigned short* Gx  = (unsigned short*)(ws + off); off += (size_t)SEQ*BATCH*NG*2;   // 100.7 MB
    unsigned short* xb  = (unsigned short*)(ws + off); off += (size_t)SEQ*BATCH*IN*2;   // 16.8 MB
    unsigned short* WxT = (unsigned short*)(ws + off); off += (size_t)NG*IN*2;
    unsigned short* WhT = (unsigned short*)(ws + off); off += (size_t)NG*HID*2;
    float* biases       = (float*)(ws + off);          off += (size_t)(NG+HID)*4;
    unsigned short* hbf = (unsigned short*)(ws + off); off += (size_t)2*BATCH*HID*2;
    unsigned* bar       = (unsigned*)(ws + off);       off += 64;
    if (ws_size < off) return;  // insufficient scratch; will fail validation loudly

    hipLaunchKernelGGL(prep_weights, dim3(6), dim3(256), 0, stream,
                       Wr, br, Wu, bu, Wni, bni, Wnh, bnh, WxT, WhT, biases);
    hipLaunchKernelGGL(cvt_x, dim3(8192), dim3(256), 0, stream, x, xb, SEQ*BATCH*IN);
    hipLaunchKernelGGL(gemm_x, dim3(512, 6), dim3(256), 0, stream, xb, WxT, biases, Gx);
    hipMemsetAsync(hbf, 0, (size_t)2*BATCH*HID*2 + 64, stream);

    void* args[] = { &Gx, &WhT, &biases, &hbf, &out, &bar };
    hipLaunchCooperativeKernel((void*)gru_seq, dim3(128), dim3(256), args, 0, stream);
}

// Round 2
// 2874.508 us; speedup vs baseline: 1.9079x; 1.9079x over previous
//
#include <hip/hip_runtime.h>
#include <hip/hip_bf16.h>

#define SEQ 512
#define BATCH 64
#define IN 256
#define HID 512
#define NG 1536  // 3*HID

typedef short short8 __attribute__((ext_vector_type(8)));
typedef float f32x4 __attribute__((ext_vector_type(4)));

__device__ __forceinline__ unsigned short f2bf(float f) {
    union { float f; unsigned u; } v; v.f = f;
    return (unsigned short)((v.u + 0x7fffu + ((v.u >> 16) & 1u)) >> 16);
}
__device__ __forceinline__ float bf2f(unsigned short h) {
    union { unsigned u; float f; } v; v.u = ((unsigned)h) << 16; return v.f;
}

// Build gate-major bf16 weight blocks + folded bias constants.
__global__ void prep_weights(const float* __restrict__ Wr, const float* __restrict__ br,
                             const float* __restrict__ Wu, const float* __restrict__ bu,
                             const float* __restrict__ Wni, const float* __restrict__ bni,
                             const float* __restrict__ Wnh, const float* __restrict__ bnh,
                             unsigned short* __restrict__ WxT, unsigned short* __restrict__ WhT,
                             float* __restrict__ biases)
{
    int n = blockIdx.x * blockDim.x + threadIdx.x;
    if (n >= NG) return;
    int g = n >> 9, j = n & 511;
    const float* xsrc; const float* hsrc; float bias;
    if (g == 0)      { xsrc = Wr + (size_t)j*770; hsrc = Wr + (size_t)j*770 + 257;
                       bias = Wr[(size_t)j*770+256] + Wr[(size_t)j*770+769] + br[j]; }
    else if (g == 1) { xsrc = Wu + (size_t)j*770; hsrc = Wu + (size_t)j*770 + 257;
                       bias = Wu[(size_t)j*770+256] + Wu[(size_t)j*770+769] + bu[j]; }
    else             { xsrc = Wni + (size_t)j*257; hsrc = Wnh + (size_t)j*513;
                       bias = Wni[(size_t)j*257+256] + bni[j]; }
    for (int i = 0; i < IN; ++i)  WxT[(size_t)n*IN + i]  = f2bf(xsrc[i]);
    for (int k = 0; k < HID; ++k) WhT[(size_t)n*HID + k] = f2bf(hsrc[k]);
    biases[n] = bias;
    if (g == 2) biases[NG + j] = Wnh[(size_t)j*513 + 512] + bnh[j];
}

__global__ void cvt_x(const float* __restrict__ x, unsigned short* __restrict__ xb, int n)
{
    int i = (blockIdx.x * blockDim.x + threadIdx.x) * 4;
    if (i >= n) return;
    float4 v = *reinterpret_cast<const float4*>(x + i);
    ushort4 o;
    o.x = f2bf(v.x); o.y = f2bf(v.y); o.z = f2bf(v.z); o.w = f2bf(v.w);
    *reinterpret_cast<ushort4*>(xb + i) = o;
}

// Gx[m][n] = sum_i xb[m][i]*WxT[n][i] + biases[n],  m = t*64+b, stored bf16.
__global__ __launch_bounds__(256) void gemm_x(const unsigned short* __restrict__ xb,
                                              const unsigned short* __restrict__ WxT,
                                              const float* __restrict__ biases,
                                              unsigned short* __restrict__ Gx)
{
    const int lane = threadIdx.x & 63;
    const int wave = threadIdx.x >> 6;
    const int m0 = blockIdx.x * 64;
    const int n0 = blockIdx.y * 256 + wave * 64;
    const int laneM = lane & 15, laneK8 = (lane >> 4) * 8;
    f32x4 acc[4][4] = {};
#pragma unroll
    for (int k0 = 0; k0 < IN; k0 += 32) {
        short8 A[4], Bf[4];
#pragma unroll
        for (int mi = 0; mi < 4; ++mi)
            A[mi] = *reinterpret_cast<const short8*>(xb + (size_t)(m0 + mi*16 + laneM)*IN + k0 + laneK8);
#pragma unroll
        for (int ni = 0; ni < 4; ++ni)
            Bf[ni] = *reinterpret_cast<const short8*>(WxT + (size_t)(n0 + ni*16 + laneM)*IN + k0 + laneK8);
#pragma unroll
        for (int mi = 0; mi < 4; ++mi)
#pragma unroll
            for (int ni = 0; ni < 4; ++ni)
                acc[mi][ni] = __builtin_amdgcn_mfma_f32_16x16x32_bf16(A[mi], Bf[ni], acc[mi][ni], 0, 0, 0);
    }
    const int crow = (lane >> 4) * 4, ccol = lane & 15;
#pragma unroll
    for (int mi = 0; mi < 4; ++mi)
#pragma unroll
        for (int ni = 0; ni < 4; ++ni) {
            int nn = n0 + ni*16 + ccol;
            float bias = biases[nn];
#pragma unroll
            for (int v = 0; v < 4; ++v) {
                int mm = m0 + mi*16 + crow + v;
                Gx[(size_t)mm * NG + nn] = f2bf(acc[mi][ni][v] + bias);
            }
        }
}

// Persistent recurrent kernel. 128 blocks x 256 threads (cooperative launch).
// 4 INDEPENDENT batch groups (mt) of 32 blocks each; sync within group only,
// via t-indexed per-wave flags + sc1 (coherence-point) data traffic.
// No acquire/release fences -> no L2 invalidate/writeback, ever.
__global__ __launch_bounds__(256) void gru_seq(const unsigned short* __restrict__ Gx,
                                               const unsigned short* __restrict__ WhT,
                                               const float* __restrict__ biases,
                                               unsigned short* __restrict__ hbf,
                                               unsigned* __restrict__ flags,
                                               float* __restrict__ out)
{
    const int blk = blockIdx.x;
    const int mt = blk >> 5, jt = blk & 31;
    const int m0 = mt * 16, j0 = jt * 16;
    const int lane = threadIdx.x & 63;
    const int wave = threadIdx.x >> 6;
    const int laneM = lane & 15, laneK8 = (lane >> 4) * 8;
    __shared__ float red[4][3][16][16];

    // Preload recurrent weight fragments once (invariant over t).
    short8 Bf[3][4];
#pragma unroll
    for (int g = 0; g < 3; ++g)
#pragma unroll
        for (int kk = 0; kk < 4; ++kk) {
            int n = g * HID + j0 + laneM;
            int k = wave * 128 + kk * 32 + laneK8;
            Bf[g][kk] = *reinterpret_cast<const short8*>(WhT + (size_t)n * HID + k);
        }

    const int row = threadIdx.x >> 4, col = threadIdx.x & 15;
    const int b = m0 + row, j = j0 + col;
    const float cnh = biases[NG + j];
    float h_old = 0.f;
    const size_t gx0 = (size_t)b * NG + j;
    unsigned short pr = Gx[gx0], pu = Gx[gx0 + HID], pn = Gx[gx0 + 2*HID];

    const unsigned* fbase = flags + (size_t)mt * SEQ * 128;  // 128 wave-flags per (group, t)

    for (int t = 0; t < SEQ; ++t) {
        // Prefetch next step's x-projections (normal cached loads, independent).
        unsigned short nr = 0, nu = 0, nn2 = 0;
        if (t + 1 < SEQ) {
            size_t gi = gx0 + (size_t)(t + 1) * BATCH * NG;
            nr = Gx[gi]; nu = Gx[gi + HID]; nn2 = Gx[gi + 2*HID];
        }

        // Wait until all 32 producer blocks (128 waves) of this group flagged step t-1.
        if (t > 0) {
            const unsigned* fp = fbase + (size_t)(t - 1) * 128;
            for (;;) {
                unsigned v0 = __hip_atomic_load(fp + lane,      __ATOMIC_RELAXED, __HIP_MEMORY_SCOPE_AGENT);
                unsigned v1 = __hip_atomic_load(fp + 64 + lane, __ATOMIC_RELAXED, __HIP_MEMORY_SCOPE_AGENT);
                if (__all(v0 && v1)) break;
            }
        }

        // Load h_t fragments via coherence-point (sc1) loads.
        const unsigned short* hcur = hbf + (size_t)(t & 1) * BATCH * HID;
        short8 A[4];
#pragma unroll
        for (int kk = 0; kk < 4; ++kk) {
            const unsigned* hp = (const unsigned*)(hcur + (size_t)(m0 + laneM) * HID + wave*128 + kk*32 + laneK8);
            union { unsigned u[4]; short8 s; } au;
#pragma unroll
            for (int w = 0; w < 4; ++w)
                au.u[w] = __hip_atomic_load(hp + w, __ATOMIC_RELAXED, __HIP_MEMORY_SCOPE_AGENT);
            A[kk] = au.s;
        }

        f32x4 aR = {0,0,0,0}, aU = {0,0,0,0}, aN = {0,0,0,0};
#pragma unroll
        for (int kk = 0; kk < 4; ++kk) {
            aR = __builtin_amdgcn_mfma_f32_16x16x32_bf16(A[kk], Bf[0][kk], aR, 0, 0, 0);
            aU = __builtin_amdgcn_mfma_f32_16x16x32_bf16(A[kk], Bf[1][kk], aU, 0, 0, 0);
            aN = __builtin_amdgcn_mfma_f32_16x16x32_bf16(A[kk], Bf[2][kk], aN, 0, 0, 0);
        }
        const int crow = (lane >> 4) * 4;
#pragma unroll
        for (int v = 0; v < 4; ++v) {
            red[wave][0][crow + v][laneM] = aR[v];
            red[wave][1][crow + v][laneM] = aU[v];
            red[wave][2][crow + v][laneM] = aN[v];
        }
        __syncthreads();
        float rp = red[0][0][row][col] + red[1][0][row][col] + red[2][0][row][col] + red[3][0][row][col];
        float up = red[0][1][row][col] + red[1][1][row][col] + red[2][1][row][col] + red[3][1][row][col];
        float np = red[0][2][row][col] + red[1][2][row][col] + red[2][2][row][col] + red[3][2][row][col];
        float r = 1.f / (1.f + __expf(-(bf2f(pr) + rp)));
        float z = 1.f / (1.f + __expf(-(bf2f(pu) + up)));
        float e = __expf(2.f * (bf2f(pn) + r * (np + cnh)));
        float n = 1.f - 2.f / (e + 1.f);
        float hnew = (1.f - z) * n + z * h_old;
        h_old = hnew;
        out[(size_t)t * BATCH * HID + (size_t)b * HID + j] = hnew;
        if (t == SEQ - 1) out[(size_t)SEQ * BATCH * HID + (size_t)b * HID + j] = hnew;

        // Store h_{t+1} (bf16 pairs packed to u32) via coherence-point stores.
        unsigned hb = (unsigned)f2bf(hnew);
        unsigned hb1 = (unsigned)__shfl_down(hb, 1);
        unsigned short* hnxt = hbf + (size_t)((t + 1) & 1) * BATCH * HID;
        if ((col & 1) == 0)
            __hip_atomic_store((unsigned*)(hnxt + (size_t)b * HID + j), hb | (hb1 << 16),
                               __ATOMIC_RELAXED, __HIP_MEMORY_SCOPE_AGENT);
        pr = nr; pu = nu; pn = nn2;

        // Drain our stores (and loads) to the coherence point, then flag this wave done.
        asm volatile("s_waitcnt vmcnt(0)" ::: "memory");
        if (lane == 0)
            __hip_atomic_store((unsigned*)(fbase + (size_t)t * 128 + jt * 4 + wave), 1u,
                               __ATOMIC_RELAXED, __HIP_MEMORY_SCOPE_AGENT);
        __syncthreads();  // WAR protection for red[] before next iteration
    }
}

extern "C" void kernel_launch(void* const* d_in, const int* in_sizes, int n_in,
                              void* d_out, int out_size, void* d_ws, size_t ws_size,
                              hipStream_t stream)
{
    const float* x   = (const float*)d_in[0];
    const float* Wr  = (const float*)d_in[1];
    const float* br  = (const float*)d_in[2];
    const float* Wu  = (const float*)d_in[3];
    const float* bu  = (const float*)d_in[4];
    const float* Wni = (const float*)d_in[5];
    const float* bni = (const float*)d_in[6];
    const float* Wnh = (const float*)d_in[7];
    const float* bnh = (const float*)d_in[8];
    float* out = (float*)d_out;

    char* ws = (char*)d_ws;
    size_t off = 0;
    unsigned short* Gx  = (unsigned short*)(ws + off); off += (size_t)SEQ*BATCH*NG*2;   // 100.7 MB
    unsigned short* xb  = (unsigned short*)(ws + off); off += (size_t)SEQ*BATCH*IN*2;   // 16.8 MB
    unsigned short* WxT = (unsigned short*)(ws + off); off += (size_t)NG*IN*2;
    unsigned short* WhT = (unsigned short*)(ws + off); off += (size_t)NG*HID*2;
    float* biases       = (float*)(ws + off);          off += (size_t)(NG+HID)*4;
    unsigned short* hbf = (unsigned short*)(ws + off); off += (size_t)2*BATCH*HID*2;    // 131 KB
    unsigned* flags     = (unsigned*)(ws + off);       off += (size_t)4*SEQ*128*4;      // 1 MB
    if (ws_size < off) return;

    hipLaunchKernelGGL(prep_weights, dim3(6), dim3(256), 0, stream,
                       Wr, br, Wu, bu, Wni, bni, Wnh, bnh, WxT, WhT, biases);
    hipLaunchKernelGGL(cvt_x, dim3(8192), dim3(256), 0, stream, x, xb, SEQ*BATCH*IN);
    hipLaunchKernelGGL(gemm_x, dim3(512, 6), dim3(256), 0, stream, xb, WxT, biases, Gx);
    // Zero h state + all flags (hbf and flags are contiguous).
    hipMemsetAsync(hbf, 0, (size_t)2*BATCH*HID*2 + (size_t)4*SEQ*128*4, stream);

    void* args[] = { &Gx, &WhT, &biases, &hbf, &flags, &out };
    hipLaunchCooperativeKernel((void*)gru_seq, dim3(128), dim3(256), args, 0, stream);
}